// Round 8
// baseline (1112.149 us; speedup 1.0000x reference)
//
#include <hip/hip_runtime.h>

#define BROWS 32768
#define DDIM 1024

typedef __bf16 bf16x8v __attribute__((ext_vector_type(8)));
typedef float f32x4v __attribute__((ext_vector_type(4)));

__device__ __forceinline__ float bf2f(unsigned short u) {
  union { unsigned int i; float f; } w; w.i = ((unsigned int)u) << 16; return w.f;
}
__device__ __forceinline__ unsigned short f2bf(float f) {
  union { float f; unsigned int i; } w; w.f = f;
  w.i += 0x7fffu + ((w.i >> 16) & 1u);   // RNE
  return (unsigned short)(w.i >> 16);
}

__device__ __forceinline__ void gl_lds16(const void* g, void* l) {
  __builtin_amdgcn_global_load_lds((const __attribute__((address_space(1))) void*)g,
                                   (__attribute__((address_space(3))) void*)l, 16, 0, 0);
}

__device__ __forceinline__ int xcd_swz(int bid, int nwg) {
  return (bid & 7) * (nwg >> 3) + (bid >> 3);
}

// ---------------- small kernels (unchanged from round 6) ----------------

__global__ __launch_bounds__(256) void cvt_x(const float* __restrict__ g,
                                             const float* __restrict__ s,
                                             unsigned short* __restrict__ xg,
                                             unsigned short* __restrict__ xs) {
  const size_t N = (size_t)BROWS * DDIM;
  size_t i = ((size_t)blockIdx.x * 256 + threadIdx.x) * 4;
  const float* src = (i < N) ? g : s;
  unsigned short* dst = (i < N) ? xg : xs;
  size_t off = (i < N) ? i : i - N;
  float4 v = *(const float4*)&src[off];
  union { uint2 q; unsigned short h[4]; } u;
  u.h[0] = f2bf(v.x); u.h[1] = f2bf(v.y); u.h[2] = f2bf(v.z); u.h[3] = f2bf(v.w);
  *(uint2*)&dst[off] = u.q;
}

__global__ __launch_bounds__(256) void cvt_wg(const float* __restrict__ s,
                                              unsigned short* __restrict__ d) {
  int i = (blockIdx.x * 256 + threadIdx.x) * 4;
  float4 v = *(const float4*)&s[i];
  union { uint2 q; unsigned short h[4]; } u;
  u.h[0] = f2bf(v.x); u.h[1] = f2bf(v.y); u.h[2] = f2bf(v.z); u.h[3] = f2bf(v.w);
  *(uint2*)&d[i] = u.q;
}

__global__ __launch_bounds__(256) void bias_combine(
    const float* __restrict__ Wo_gs, const float* __restrict__ bv_gs,
    const float* __restrict__ bo_gs,
    const float* __restrict__ Wo_sg, const float* __restrict__ bv_sg,
    const float* __restrict__ bo_sg,
    float* __restrict__ bc_gs, float* __restrict__ bc_sg) {
  int gid = blockIdx.x * 256 + threadIdx.x;
  int pair = gid >> 10, j = gid & 1023;
  const float* Wo = pair ? Wo_sg : Wo_gs;
  const float* bv = pair ? bv_sg : bv_gs;
  const float* bo = pair ? bo_sg : bo_gs;
  float s = 0.f;
  for (int k = 0; k < DDIM; k += 4) {
    float4 w = *(const float4*)&Wo[(size_t)j * DDIM + k];
    float4 b = *(const float4*)&bv[k];
    s += w.x * b.x + w.y * b.y + w.z * b.z + w.w * b.w;
  }
  float* bc = pair ? bc_sg : bc_gs;
  bc[j] = s + bo[j];
}

// f32 -> bf16 [128][32] LDS tile (combine + gate fallback), 256 threads.
__device__ __forceinline__ void stage_f32(const float* __restrict__ src, int ldk,
                                          int row0, int k0, unsigned short* lds, int tid) {
  const int sr = tid >> 2, sc = (tid & 3) * 8;
#pragma unroll
  for (int h = 0; h < 2; ++h) {
    const float* g = &src[(size_t)(row0 + h * 64 + sr) * ldk + k0 + sc];
    float4 va = ((const float4*)g)[0];
    float4 vb = ((const float4*)g)[1];
    union { uint4 q; unsigned short hh[8]; } u;
    u.hh[0] = f2bf(va.x); u.hh[1] = f2bf(va.y); u.hh[2] = f2bf(va.z); u.hh[3] = f2bf(va.w);
    u.hh[4] = f2bf(vb.x); u.hh[5] = f2bf(vb.y); u.hh[6] = f2bf(vb.z); u.hh[7] = f2bf(vb.w);
    *(uint4*)&lds[(h * 64 + sr) * 32 + sc] = u.q;
  }
}

__device__ __forceinline__ void mfma_tile128(const unsigned short* As, const unsigned short* Bs,
                                             int ab, int bb, f32x4v acc[4][4]) {
  const bf16x8v* Av = reinterpret_cast<const bf16x8v*>(As);
  const bf16x8v* Bv = reinterpret_cast<const bf16x8v*>(Bs);
  bf16x8v af[4], bfr[4];
#pragma unroll
  for (int m = 0; m < 4; ++m) af[m] = Av[ab + m * 64];
#pragma unroll
  for (int n = 0; n < 4; ++n) bfr[n] = Bv[bb + n * 64];
#pragma unroll
  for (int m = 0; m < 4; ++m)
#pragma unroll
    for (int n = 0; n < 4; ++n)
      acc[m][n] = __builtin_amdgcn_mfma_f32_16x16x32_bf16(af[m], bfr[n], acc[m][n], 0, 0, 0);
}

// Wc = Wo @ Wv (1024^3 NN, f32 in, bf16 out) — 128^2 tile, small kernel.
__global__ __launch_bounds__(256) void combine_kernel(
    const float* __restrict__ Wo_gs, const float* __restrict__ Wv_gs,
    const float* __restrict__ Wo_sg, const float* __restrict__ Wv_sg,
    unsigned short* __restrict__ Wc_gs, unsigned short* __restrict__ Wc_sg) {
  const int pair = blockIdx.y;
  const float* Wo = pair ? Wo_sg : Wo_gs;
  const float* Wv = pair ? Wv_sg : Wv_gs;
  unsigned short* Wc = pair ? Wc_sg : Wc_gs;
  const int mt = blockIdx.x >> 3, nt = blockIdx.x & 7;
  const int row0 = mt * 128, col0 = nt * 128;

  __shared__ __align__(16) unsigned short As[128 * 32];
  __shared__ __align__(16) unsigned short Bt[128 * 32];

  const int tid = threadIdx.x;
  const int lane = tid & 63, wave = tid >> 6;
  const int wr = wave >> 1, wc = wave & 1;
  const int lr = lane & 15, lk = lane >> 4;

  f32x4v acc[4][4] = {};
  const int ab = (wr * 64 + lr) * 4 + lk;
  const int bb = (wc * 64 + lr) * 4 + lk;

  for (int tt = 0; tt < 32; ++tt) {
    const int t0 = tt * 32;
    __syncthreads();
    stage_f32(Wo, DDIM, row0, t0, As, tid);
#pragma unroll
    for (int h = 0; h < 2; ++h) {
      int chunk = h * 256 + tid;
      int t = chunk >> 4;
      int c8 = (chunk & 15) * 8;
      const float* g = &Wv[(size_t)(t0 + t) * DDIM + col0 + c8];
      float4 va = ((const float4*)g)[0];
      float4 vb = ((const float4*)g)[1];
      float vv[8] = {va.x, va.y, va.z, va.w, vb.x, vb.y, vb.z, vb.w};
#pragma unroll
      for (int e = 0; e < 8; ++e) Bt[(c8 + e) * 32 + t] = f2bf(vv[e]);
    }
    __syncthreads();
    mfma_tile128(As, Bt, ab, bb, acc);
  }

#pragma unroll
  for (int n = 0; n < 4; ++n) {
    int col = col0 + wc * 64 + n * 16 + lr;
#pragma unroll
    for (int m = 0; m < 4; ++m) {
      int rbase = row0 + wr * 64 + m * 16 + lk * 4;
#pragma unroll
      for (int r = 0; r < 4; ++r)
        Wc[(size_t)(rbase + r) * DDIM + col] = f2bf(acc[m][n][r]);
    }
  }
}

// ---------------- 256^2 / BK=64 / 8-wave dbuf GEMM core ----------------
// Per wave (2x4 grid): 128x64 output = acc[8][4] fragments of 16x16x32.
// LDS 128 KiB (2 dbuf x (A,B) x 256x64 bf16). Staging: 8 gl_lds/tile/thread.

#define MFMA256_COMPUTE(Asrc, Bsrc)                                              \
  {                                                                              \
    const bf16x8v* Av = reinterpret_cast<const bf16x8v*>(Asrc);                  \
    const bf16x8v* Bv = reinterpret_cast<const bf16x8v*>(Bsrc);                  \
    _Pragma("unroll")                                                            \
    for (int s = 0; s < 2; ++s) {                                                \
      bf16x8v av[8], bvv[4];                                                     \
      _Pragma("unroll")                                                          \
      for (int m = 0; m < 8; ++m) av[m] = Av[(wm*128 + m*16 + lr)*8 + s*4 + lk]; \
      _Pragma("unroll")                                                          \
      for (int n = 0; n < 4; ++n) bvv[n] = Bv[(wn*64 + n*16 + lr)*8 + s*4 + lk]; \
      _Pragma("unroll")                                                          \
      for (int m = 0; m < 8; ++m)                                                \
        _Pragma("unroll")                                                        \
        for (int n = 0; n < 4; ++n)                                              \
          acc[m][n] = __builtin_amdgcn_mfma_f32_16x16x32_bf16(av[m], bvv[n],     \
                                                              acc[m][n], 0, 0, 0);\
    }                                                                            \
  }

// Z = bf16( Xb @ Wc^T + bc + resid )  [256^2 tile]
__global__ __launch_bounds__(512, 2) void gemm_branch256(
    const unsigned short* __restrict__ Xs_b, const unsigned short* __restrict__ Xg_b,
    const float* __restrict__ smiles, const float* __restrict__ graph,
    const unsigned short* __restrict__ Wc_gs, const unsigned short* __restrict__ Wc_sg,
    const float* __restrict__ bc_gs, const float* __restrict__ bc_sg,
    unsigned short* __restrict__ Zg, unsigned short* __restrict__ Zs) {
  const int pair = blockIdx.y;
  const unsigned short* X = pair ? Xg_b : Xs_b;
  const unsigned short* Wc = pair ? Wc_sg : Wc_gs;
  const float* bc = pair ? bc_sg : bc_gs;
  const float* resid = pair ? smiles : graph;
  unsigned short* Z = pair ? Zs : Zg;

  const int bid = xcd_swz(blockIdx.x, 512);
  const int mt = bid >> 2, nt = bid & 3;
  const int row0 = mt * 256, col0 = nt * 256;

  __shared__ __align__(16) unsigned short As[2][256 * 64];
  __shared__ __align__(16) unsigned short Bs[2][256 * 64];

  const int tid = threadIdx.x;
  const int lane = tid & 63, wave = tid >> 6;
  const int wm = wave >> 2, wn = wave & 3;
  const int lr = lane & 15, lk = lane >> 4;
  const int srow = tid >> 3, scol8 = (tid & 7) * 8;

  f32x4v acc[8][4] = {};

  auto stage = [&](int b, int kt) {
    const int k0 = kt * 64;
#pragma unroll
    for (int h = 0; h < 4; ++h)
      gl_lds16(&X[(size_t)(row0 + h * 64 + srow) * DDIM + k0 + scol8],
               &As[b][h * 4096 + tid * 8]);
#pragma unroll
    for (int h = 0; h < 4; ++h)
      gl_lds16(&Wc[(size_t)(col0 + h * 64 + srow) * DDIM + k0 + scol8],
               &Bs[b][h * 4096 + tid * 8]);
  };

  stage(0, 0);
  for (int kt = 0; kt < 16; ++kt) {
    const int b = kt & 1;
    if (kt + 1 < 16) {
      stage(b ^ 1, kt + 1);
      asm volatile("s_waitcnt vmcnt(8)" ::: "memory");
    } else {
      asm volatile("s_waitcnt vmcnt(0)" ::: "memory");
    }
    __builtin_amdgcn_sched_barrier(0);
    __builtin_amdgcn_s_barrier();
    __builtin_amdgcn_sched_barrier(0);
    MFMA256_COMPUTE(As[b], Bs[b]);
    __builtin_amdgcn_sched_barrier(0);
    asm volatile("s_waitcnt lgkmcnt(0)" ::: "memory");
    __builtin_amdgcn_s_barrier();
    __builtin_amdgcn_sched_barrier(0);
  }

#pragma unroll
  for (int n = 0; n < 4; ++n) {
    int col = col0 + wn * 64 + n * 16 + lr;
    float bcv = bc[col];
#pragma unroll
    for (int m = 0; m < 8; ++m) {
      int rbase = row0 + wm * 128 + m * 16 + lk * 4;
#pragma unroll
      for (int r = 0; r < 4; ++r) {
        size_t idx = (size_t)(rbase + r) * DDIM + col;
        Z[idx] = f2bf(acc[m][n][r] + bcv + resid[idx]);
      }
    }
  }
}

// gate = sigmoid([fg,fs] @ WgB^T + bg); out0/out1 f32.  [256^2 tile]
__global__ __launch_bounds__(512, 2) void gemm_gate256(
    const unsigned short* __restrict__ fg, const unsigned short* __restrict__ fs,
    const unsigned short* __restrict__ WgB, const float* __restrict__ bg,
    float* __restrict__ out0, float* __restrict__ out1) {
  const int bid = xcd_swz(blockIdx.x, 512);
  const int mt = bid >> 2, nt = bid & 3;
  const int row0 = mt * 256, col0 = nt * 256;

  __shared__ __align__(16) unsigned short As[2][256 * 64];
  __shared__ __align__(16) unsigned short Bs[2][256 * 64];

  const int tid = threadIdx.x;
  const int lane = tid & 63, wave = tid >> 6;
  const int wm = wave >> 2, wn = wave & 3;
  const int lr = lane & 15, lk = lane >> 4;
  const int srow = tid >> 3, scol8 = (tid & 7) * 8;

  f32x4v acc[8][4] = {};

  auto stage = [&](int b, int kt) {
    const unsigned short* Asrc = (kt < 16) ? fg : fs;
    const int k0 = (kt & 15) * 64;
    const int kw = kt * 64;
#pragma unroll
    for (int h = 0; h < 4; ++h)
      gl_lds16(&Asrc[(size_t)(row0 + h * 64 + srow) * DDIM + k0 + scol8],
               &As[b][h * 4096 + tid * 8]);
#pragma unroll
    for (int h = 0; h < 4; ++h)
      gl_lds16(&WgB[(size_t)(col0 + h * 64 + srow) * 2048 + kw + scol8],
               &Bs[b][h * 4096 + tid * 8]);
  };

  stage(0, 0);
  for (int kt = 0; kt < 32; ++kt) {
    const int b = kt & 1;
    if (kt + 1 < 32) {
      stage(b ^ 1, kt + 1);
      asm volatile("s_waitcnt vmcnt(8)" ::: "memory");
    } else {
      asm volatile("s_waitcnt vmcnt(0)" ::: "memory");
    }
    __builtin_amdgcn_sched_barrier(0);
    __builtin_amdgcn_s_barrier();
    __builtin_amdgcn_sched_barrier(0);
    MFMA256_COMPUTE(As[b], Bs[b]);
    __builtin_amdgcn_sched_barrier(0);
    asm volatile("s_waitcnt lgkmcnt(0)" ::: "memory");
    __builtin_amdgcn_s_barrier();
    __builtin_amdgcn_sched_barrier(0);
  }

#pragma unroll
  for (int n = 0; n < 4; ++n) {
    int col = col0 + wn * 64 + n * 16 + lr;
    float bgv = bg[col];
#pragma unroll
    for (int m = 0; m < 8; ++m) {
      int rbase = row0 + wm * 128 + m * 16 + lk * 4;
#pragma unroll
      for (int r = 0; r < 4; ++r) {
        size_t idx = (size_t)(rbase + r) * DDIM + col;
        float g = 1.f / (1.f + __expf(-(acc[m][n][r] + bgv)));
        float a = bf2f(fg[idx]), b2 = bf2f(fs[idx]);
        out0[idx] = g * a + (1.f - g) * b2;
        out1[idx] = g;
      }
    }
  }
}

// Fallback gate (128^2, B reg-staged from f32 Wg) — only if d_ws < 132 MiB.
__global__ __launch_bounds__(256) void gemm_gate128_f32(
    const unsigned short* __restrict__ fg, const unsigned short* __restrict__ fs,
    const float* __restrict__ Wg, const float* __restrict__ bg,
    float* __restrict__ out0, float* __restrict__ out1) {
  const int bid = xcd_swz(blockIdx.x, 2048);
  const int mt = bid >> 3, nt = bid & 7;
  const int row0 = mt * 128, col0 = nt * 128;

  __shared__ __align__(16) unsigned short As[128 * 32];
  __shared__ __align__(16) unsigned short Bss[128 * 32];

  const int tid = threadIdx.x;
  const int lane = tid & 63, wave = tid >> 6;
  const int wr = wave >> 1, wc = wave & 1;
  const int lr = lane & 15, lk = lane >> 4;
  const int sr = tid >> 2, sc = (tid & 3) * 8;

  f32x4v acc[4][4] = {};
  const int ab = (wr * 64 + lr) * 4 + lk;
  const int bb = (wc * 64 + lr) * 4 + lk;

  for (int kt = 0; kt < 64; ++kt) {
    const unsigned short* Asrc = (kt < 32) ? fg : fs;
    const int k0 = (kt & 31) * 32;
    const int kw = kt * 32;
    __syncthreads();
    gl_lds16(&Asrc[(size_t)(row0 + sr) * DDIM + k0 + sc], &As[sr * 32 + sc]);
    gl_lds16(&Asrc[(size_t)(row0 + 64 + sr) * DDIM + k0 + sc], &As[(64 + sr) * 32 + sc]);
    stage_f32(Wg, 2048, col0, kw, Bss, tid);
    __syncthreads();
    mfma_tile128(As, Bss, ab, bb, acc);
  }

#pragma unroll
  for (int n = 0; n < 4; ++n) {
    int col = col0 + wc * 64 + n * 16 + lr;
    float bgv = bg[col];
#pragma unroll
    for (int m = 0; m < 4; ++m) {
      int rbase = row0 + wr * 64 + m * 16 + lk * 4;
#pragma unroll
      for (int r = 0; r < 4; ++r) {
        size_t idx = (size_t)(rbase + r) * DDIM + col;
        float g = 1.f / (1.f + __expf(-(acc[m][n][r] + bgv)));
        float a = bf2f(fg[idx]), b = bf2f(fs[idx]);
        out0[idx] = g * a + (1.f - g) * b;
        out1[idx] = g;
      }
    }
  }
}

// In-place LayerNorm over rows of Z. 1 wave per row.
__global__ __launch_bounds__(256) void ln_kernel(
    unsigned short* __restrict__ Z,
    const float* __restrict__ gam_g, const float* __restrict__ bet_g,
    const float* __restrict__ gam_s, const float* __restrict__ bet_s) {
  int row = blockIdx.x * 4 + (threadIdx.x >> 6);
  int lane = threadIdx.x & 63;
  const float* gam = (row < BROWS) ? gam_g : gam_s;
  const float* bet = (row < BROWS) ? bet_g : bet_s;
  unsigned short* zr = Z + (size_t)row * DDIM;

  uint4 v0 = *(const uint4*)(zr + lane * 8);
  uint4 v1 = *(const uint4*)(zr + 512 + lane * 8);
  const unsigned short* u0 = (const unsigned short*)&v0;
  const unsigned short* u1 = (const unsigned short*)&v1;
  float x[16];
  float s = 0.f, sq = 0.f;
#pragma unroll
  for (int e = 0; e < 8; ++e) { x[e] = bf2f(u0[e]); x[8 + e] = bf2f(u1[e]); }
#pragma unroll
  for (int i = 0; i < 16; ++i) { s += x[i]; sq += x[i] * x[i]; }
#pragma unroll
  for (int o = 32; o; o >>= 1) { s += __shfl_xor(s, o); sq += __shfl_xor(sq, o); }
  float mu = s * (1.f / 1024.f);
  float var = sq * (1.f / 1024.f) - mu * mu;
  float rstd = rsqrtf(var + 1e-5f);

  float4 g0 = *(const float4*)(gam + lane * 8);
  float4 g1 = *(const float4*)(gam + lane * 8 + 4);
  float4 g2 = *(const float4*)(gam + 512 + lane * 8);
  float4 g3 = *(const float4*)(gam + 512 + lane * 8 + 4);
  float4 b0 = *(const float4*)(bet + lane * 8);
  float4 b1 = *(const float4*)(bet + lane * 8 + 4);
  float4 b2 = *(const float4*)(bet + 512 + lane * 8);
  float4 b3 = *(const float4*)(bet + 512 + lane * 8 + 4);
  float gg[16] = {g0.x,g0.y,g0.z,g0.w,g1.x,g1.y,g1.z,g1.w,
                  g2.x,g2.y,g2.z,g2.w,g3.x,g3.y,g3.z,g3.w};
  float bb[16] = {b0.x,b0.y,b0.z,b0.w,b1.x,b1.y,b1.z,b1.w,
                  b2.x,b2.y,b2.z,b2.w,b3.x,b3.y,b3.z,b3.w};

  union { uint4 q; unsigned short h[8]; } o0, o1;
#pragma unroll
  for (int e = 0; e < 8; ++e) {
    o0.h[e] = f2bf((x[e] - mu) * rstd * gg[e] + bb[e]);
    o1.h[e] = f2bf((x[8 + e] - mu) * rstd * gg[8 + e] + bb[8 + e]);
  }
  *(uint4*)(zr + lane * 8) = o0.q;
  *(uint4*)(zr + 512 + lane * 8) = o1.q;
}

extern "C" void kernel_launch(void* const* d_in, const int* in_sizes, int n_in,
                              void* d_out, int out_size, void* d_ws, size_t ws_size,
                              hipStream_t stream) {
  const float* graph  = (const float*)d_in[0];
  const float* smiles = (const float*)d_in[1];
  const float* bv_gs  = (const float*)d_in[8];
  const float* Wv_gs  = (const float*)d_in[5];
  const float* Wo_gs  = (const float*)d_in[9];
  const float* bo_gs  = (const float*)d_in[10];
  const float* Wv_sg  = (const float*)d_in[13];
  const float* bv_sg  = (const float*)d_in[16];
  const float* Wo_sg  = (const float*)d_in[17];
  const float* bo_sg  = (const float*)d_in[18];
  const float* ln_gg  = (const float*)d_in[19];
  const float* ln_gb  = (const float*)d_in[20];
  const float* ln_sg  = (const float*)d_in[21];
  const float* ln_sb  = (const float*)d_in[22];
  const float* Wg     = (const float*)d_in[23];
  const float* bg     = (const float*)d_in[24];

  char* ob = (char*)d_out;
  unsigned short* Xg_b  = (unsigned short*)ob;                        // 64 MiB
  unsigned short* Xs_b  = (unsigned short*)(ob + (64u << 20));        // 64 MiB
  unsigned short* Wc_gs = (unsigned short*)(ob + (128u << 20));       // 2 MiB
  unsigned short* Wc_sg = (unsigned short*)(ob + (130u << 20));       // 2 MiB
  float* bc_gs = (float*)(ob + (132u << 20));
  float* bc_sg = (float*)(ob + (132u << 20) + 4096);

  unsigned short* Zg = (unsigned short*)d_ws;
  unsigned short* Zs = Zg + (size_t)BROWS * DDIM;
  const bool fast = ws_size >= ((size_t)132 << 20);
  unsigned short* WgB = (unsigned short*)((char*)d_ws + ((size_t)128 << 20));

  float* out0 = (float*)d_out;
  float* out1 = out0 + (size_t)BROWS * DDIM;

  cvt_x<<<dim3(65536), dim3(256), 0, stream>>>(graph, smiles, Xg_b, Xs_b);
  bias_combine<<<dim3(8), dim3(256), 0, stream>>>(Wo_gs, bv_gs, bo_gs, Wo_sg, bv_sg, bo_sg,
                                                  bc_gs, bc_sg);
  combine_kernel<<<dim3(64, 2), dim3(256), 0, stream>>>(Wo_gs, Wv_gs, Wo_sg, Wv_sg,
                                                        Wc_gs, Wc_sg);
  if (fast) cvt_wg<<<dim3(2048), dim3(256), 0, stream>>>(Wg, WgB);
  gemm_branch256<<<dim3(512, 2), dim3(512), 0, stream>>>(Xs_b, Xg_b, smiles, graph,
                                                         Wc_gs, Wc_sg, bc_gs, bc_sg, Zg, Zs);
  ln_kernel<<<dim3(16384), dim3(256), 0, stream>>>(Zg, ln_gg, ln_gb, ln_sg, ln_sb);
  if (fast)
    gemm_gate256<<<dim3(512), dim3(512), 0, stream>>>(Zg, Zs, WgB, bg, out0, out1);
  else
    gemm_gate128_f32<<<dim3(2048), dim3(256), 0, stream>>>(Zg, Zs, Wg, bg, out0, out1);
}

// Round 9
// 841.496 us; speedup vs baseline: 1.3216x; 1.3216x over previous
//
#include <hip/hip_runtime.h>

#define BROWS 32768
#define DDIM 1024

typedef __bf16 bf16x8v __attribute__((ext_vector_type(8)));
typedef float f32x4v __attribute__((ext_vector_type(4)));

__device__ __forceinline__ float bf2f(unsigned short u) {
  union { unsigned int i; float f; } w; w.i = ((unsigned int)u) << 16; return w.f;
}
__device__ __forceinline__ unsigned short f2bf(float f) {
  union { float f; unsigned int i; } w; w.f = f;
  w.i += 0x7fffu + ((w.i >> 16) & 1u);   // RNE
  return (unsigned short)(w.i >> 16);
}

__device__ __forceinline__ void gl_lds16(const void* g, void* l) {
  __builtin_amdgcn_global_load_lds((const __attribute__((address_space(1))) void*)g,
                                   (__attribute__((address_space(3))) void*)l, 16, 0, 0);
}

__device__ __forceinline__ int xcd_swz(int bid, int nwg) {
  return (bid & 7) * (nwg >> 3) + (bid >> 3);
}

// ---------------- small kernels (unchanged from round 6) ----------------

__global__ __launch_bounds__(256) void cvt_x(const float* __restrict__ g,
                                             const float* __restrict__ s,
                                             unsigned short* __restrict__ xg,
                                             unsigned short* __restrict__ xs) {
  const size_t N = (size_t)BROWS * DDIM;
  size_t i = ((size_t)blockIdx.x * 256 + threadIdx.x) * 4;
  const float* src = (i < N) ? g : s;
  unsigned short* dst = (i < N) ? xg : xs;
  size_t off = (i < N) ? i : i - N;
  float4 v = *(const float4*)&src[off];
  union { uint2 q; unsigned short h[4]; } u;
  u.h[0] = f2bf(v.x); u.h[1] = f2bf(v.y); u.h[2] = f2bf(v.z); u.h[3] = f2bf(v.w);
  *(uint2*)&dst[off] = u.q;
}

__global__ __launch_bounds__(256) void cvt_wg(const float* __restrict__ s,
                                              unsigned short* __restrict__ d) {
  int i = (blockIdx.x * 256 + threadIdx.x) * 4;
  float4 v = *(const float4*)&s[i];
  union { uint2 q; unsigned short h[4]; } u;
  u.h[0] = f2bf(v.x); u.h[1] = f2bf(v.y); u.h[2] = f2bf(v.z); u.h[3] = f2bf(v.w);
  *(uint2*)&d[i] = u.q;
}

__global__ __launch_bounds__(256) void bias_combine(
    const float* __restrict__ Wo_gs, const float* __restrict__ bv_gs,
    const float* __restrict__ bo_gs,
    const float* __restrict__ Wo_sg, const float* __restrict__ bv_sg,
    const float* __restrict__ bo_sg,
    float* __restrict__ bc_gs, float* __restrict__ bc_sg) {
  int gid = blockIdx.x * 256 + threadIdx.x;
  int pair = gid >> 10, j = gid & 1023;
  const float* Wo = pair ? Wo_sg : Wo_gs;
  const float* bv = pair ? bv_sg : bv_gs;
  const float* bo = pair ? bo_sg : bo_gs;
  float s = 0.f;
  for (int k = 0; k < DDIM; k += 4) {
    float4 w = *(const float4*)&Wo[(size_t)j * DDIM + k];
    float4 b = *(const float4*)&bv[k];
    s += w.x * b.x + w.y * b.y + w.z * b.z + w.w * b.w;
  }
  float* bc = pair ? bc_sg : bc_gs;
  bc[j] = s + bo[j];
}

// f32 -> bf16 [128][32] LDS tile (combine + gate fallback), 256 threads.
__device__ __forceinline__ void stage_f32(const float* __restrict__ src, int ldk,
                                          int row0, int k0, unsigned short* lds, int tid) {
  const int sr = tid >> 2, sc = (tid & 3) * 8;
#pragma unroll
  for (int h = 0; h < 2; ++h) {
    const float* g = &src[(size_t)(row0 + h * 64 + sr) * ldk + k0 + sc];
    float4 va = ((const float4*)g)[0];
    float4 vb = ((const float4*)g)[1];
    union { uint4 q; unsigned short hh[8]; } u;
    u.hh[0] = f2bf(va.x); u.hh[1] = f2bf(va.y); u.hh[2] = f2bf(va.z); u.hh[3] = f2bf(va.w);
    u.hh[4] = f2bf(vb.x); u.hh[5] = f2bf(vb.y); u.hh[6] = f2bf(vb.z); u.hh[7] = f2bf(vb.w);
    *(uint4*)&lds[(h * 64 + sr) * 32 + sc] = u.q;
  }
}

// 16x16x32 MFMA over one [128][32] A tile and one [128][32] B tile.
__device__ __forceinline__ void mfma_tile128(const unsigned short* As, const unsigned short* Bs,
                                             int ab, int bb, f32x4v acc[4][4]) {
  const bf16x8v* Av = reinterpret_cast<const bf16x8v*>(As);
  const bf16x8v* Bv = reinterpret_cast<const bf16x8v*>(Bs);
  bf16x8v af[4], bfr[4];
#pragma unroll
  for (int m = 0; m < 4; ++m) af[m] = Av[ab + m * 64];
#pragma unroll
  for (int n = 0; n < 4; ++n) bfr[n] = Bv[bb + n * 64];
#pragma unroll
  for (int m = 0; m < 4; ++m)
#pragma unroll
    for (int n = 0; n < 4; ++n)
      acc[m][n] = __builtin_amdgcn_mfma_f32_16x16x32_bf16(af[m], bfr[n], acc[m][n], 0, 0, 0);
}

// Wc = Wo @ Wv (1024^3 NN, f32 in, bf16 out) — 128^2 tile, small kernel.
__global__ __launch_bounds__(256) void combine_kernel(
    const float* __restrict__ Wo_gs, const float* __restrict__ Wv_gs,
    const float* __restrict__ Wo_sg, const float* __restrict__ Wv_sg,
    unsigned short* __restrict__ Wc_gs, unsigned short* __restrict__ Wc_sg) {
  const int pair = blockIdx.y;
  const float* Wo = pair ? Wo_sg : Wo_gs;
  const float* Wv = pair ? Wv_sg : Wv_gs;
  unsigned short* Wc = pair ? Wc_sg : Wc_gs;
  const int mt = blockIdx.x >> 3, nt = blockIdx.x & 7;
  const int row0 = mt * 128, col0 = nt * 128;

  __shared__ __align__(16) unsigned short As[128 * 32];
  __shared__ __align__(16) unsigned short Bt[128 * 32];

  const int tid = threadIdx.x;
  const int lane = tid & 63, wave = tid >> 6;
  const int wr = wave >> 1, wc = wave & 1;
  const int lr = lane & 15, lk = lane >> 4;

  f32x4v acc[4][4] = {};
  const int ab = (wr * 64 + lr) * 4 + lk;
  const int bb = (wc * 64 + lr) * 4 + lk;

  for (int tt = 0; tt < 32; ++tt) {
    const int t0 = tt * 32;
    __syncthreads();
    stage_f32(Wo, DDIM, row0, t0, As, tid);
#pragma unroll
    for (int h = 0; h < 2; ++h) {
      int chunk = h * 256 + tid;
      int t = chunk >> 4;
      int c8 = (chunk & 15) * 8;
      const float* g = &Wv[(size_t)(t0 + t) * DDIM + col0 + c8];
      float4 va = ((const float4*)g)[0];
      float4 vb = ((const float4*)g)[1];
      float vv[8] = {va.x, va.y, va.z, va.w, vb.x, vb.y, vb.z, vb.w};
#pragma unroll
      for (int e = 0; e < 8; ++e) Bt[(c8 + e) * 32 + t] = f2bf(vv[e]);
    }
    __syncthreads();
    mfma_tile128(As, Bt, ab, bb, acc);
  }

#pragma unroll
  for (int n = 0; n < 4; ++n) {
    int col = col0 + wc * 64 + n * 16 + lr;
#pragma unroll
    for (int m = 0; m < 4; ++m) {
      int rbase = row0 + wr * 64 + m * 16 + lk * 4;
#pragma unroll
      for (int r = 0; r < 4; ++r)
        Wc[(size_t)(rbase + r) * DDIM + col] = f2bf(acc[m][n][r]);
    }
  }
}

// ---- 128^2 / BK=64 split-slot GEMM (r6 skeleton, 2x MFMA per barrier pair) ----
// LDS: 4 x [128][32] tiles (As0,As1,Bs0,Bs1) = 32 KB. 64B row stride preserved.

// Z = bf16( Xb @ Wc^T + bc + residb(bf16) )
__global__ __launch_bounds__(256) void gemm_branch(
    const unsigned short* __restrict__ Xs_b, const unsigned short* __restrict__ Xg_b,
    const unsigned short* __restrict__ Wc_gs, const unsigned short* __restrict__ Wc_sg,
    const float* __restrict__ bc_gs, const float* __restrict__ bc_sg,
    unsigned short* __restrict__ Zg, unsigned short* __restrict__ Zs) {
  const int pair = blockIdx.y;
  const unsigned short* X = pair ? Xg_b : Xs_b;
  const unsigned short* residb = pair ? Xs_b : Xg_b;
  const unsigned short* Wc = pair ? Wc_sg : Wc_gs;
  const float* bc = pair ? bc_sg : bc_gs;
  unsigned short* Z = pair ? Zs : Zg;

  const int bid = xcd_swz(blockIdx.x, 2048);
  const int mt = bid >> 3, nt = bid & 7;
  const int row0 = mt * 128, col0 = nt * 128;

  __shared__ __align__(16) unsigned short As0[128 * 32];
  __shared__ __align__(16) unsigned short As1[128 * 32];
  __shared__ __align__(16) unsigned short Bs0[128 * 32];
  __shared__ __align__(16) unsigned short Bs1[128 * 32];

  const int tid = threadIdx.x;
  const int lane = tid & 63, wave = tid >> 6;
  const int wr = wave >> 1, wc = wave & 1;
  const int lr = lane & 15, lk = lane >> 4;

  f32x4v acc[4][4] = {};
  const int ab = (wr * 64 + lr) * 4 + lk;
  const int bb = (wc * 64 + lr) * 4 + lk;

  for (int kt = 0; kt < 16; ++kt) {
    const int k0 = kt * 64;
    __syncthreads();
#pragma unroll
    for (int h = 0; h < 2; ++h) {
      const int e0 = h * 2048 + tid * 8;          // element in [128][32] tile
      const int row = e0 >> 5, colc = e0 & 31;
      gl_lds16(&X[(size_t)(row0 + row) * DDIM + k0 + colc], &As0[e0]);
      gl_lds16(&X[(size_t)(row0 + row) * DDIM + k0 + 32 + colc], &As1[e0]);
      gl_lds16(&Wc[(size_t)(col0 + row) * DDIM + k0 + colc], &Bs0[e0]);
      gl_lds16(&Wc[(size_t)(col0 + row) * DDIM + k0 + 32 + colc], &Bs1[e0]);
    }
    __syncthreads();
    mfma_tile128(As0, Bs0, ab, bb, acc);
    mfma_tile128(As1, Bs1, ab, bb, acc);
  }

#pragma unroll
  for (int n = 0; n < 4; ++n) {
    int col = col0 + wc * 64 + n * 16 + lr;
    float bcv = bc[col];
#pragma unroll
    for (int m = 0; m < 4; ++m) {
      int rbase = row0 + wr * 64 + m * 16 + lk * 4;
#pragma unroll
      for (int r = 0; r < 4; ++r) {
        size_t idx = (size_t)(rbase + r) * DDIM + col;
        Z[idx] = f2bf(acc[m][n][r] + bcv + bf2f(residb[idx]));
      }
    }
  }
}

// gate = sigmoid([fg,fs] @ WgB^T + bg); out0/out1 f32.
__global__ __launch_bounds__(256) void gemm_gate(
    const unsigned short* __restrict__ fg, const unsigned short* __restrict__ fs,
    const unsigned short* __restrict__ WgB, const float* __restrict__ bg,
    float* __restrict__ out0, float* __restrict__ out1) {
  const int bid = xcd_swz(blockIdx.x, 2048);
  const int mt = bid >> 3, nt = bid & 7;
  const int row0 = mt * 128, col0 = nt * 128;

  __shared__ __align__(16) unsigned short As0[128 * 32];
  __shared__ __align__(16) unsigned short As1[128 * 32];
  __shared__ __align__(16) unsigned short Bs0[128 * 32];
  __shared__ __align__(16) unsigned short Bs1[128 * 32];

  const int tid = threadIdx.x;
  const int lane = tid & 63, wave = tid >> 6;
  const int wr = wave >> 1, wc = wave & 1;
  const int lr = lane & 15, lk = lane >> 4;

  f32x4v acc[4][4] = {};
  const int ab = (wr * 64 + lr) * 4 + lk;
  const int bb = (wc * 64 + lr) * 4 + lk;

  for (int kt = 0; kt < 32; ++kt) {
    const unsigned short* Asrc = (kt < 16) ? fg : fs;
    const int k0 = (kt & 15) * 64;
    const int kw = kt * 64;
    __syncthreads();
#pragma unroll
    for (int h = 0; h < 2; ++h) {
      const int e0 = h * 2048 + tid * 8;
      const int row = e0 >> 5, colc = e0 & 31;
      gl_lds16(&Asrc[(size_t)(row0 + row) * DDIM + k0 + colc], &As0[e0]);
      gl_lds16(&Asrc[(size_t)(row0 + row) * DDIM + k0 + 32 + colc], &As1[e0]);
      gl_lds16(&WgB[(size_t)(col0 + row) * 2048 + kw + colc], &Bs0[e0]);
      gl_lds16(&WgB[(size_t)(col0 + row) * 2048 + kw + 32 + colc], &Bs1[e0]);
    }
    __syncthreads();
    mfma_tile128(As0, Bs0, ab, bb, acc);
    mfma_tile128(As1, Bs1, ab, bb, acc);
  }

#pragma unroll
  for (int n = 0; n < 4; ++n) {
    int col = col0 + wc * 64 + n * 16 + lr;
    float bgv = bg[col];
#pragma unroll
    for (int m = 0; m < 4; ++m) {
      int rbase = row0 + wr * 64 + m * 16 + lk * 4;
#pragma unroll
      for (int r = 0; r < 4; ++r) {
        size_t idx = (size_t)(rbase + r) * DDIM + col;
        float g = 1.f / (1.f + __expf(-(acc[m][n][r] + bgv)));
        float a = bf2f(fg[idx]), b = bf2f(fs[idx]);
        out0[idx] = g * a + (1.f - g) * b;
        out1[idx] = g;
      }
    }
  }
}

// Fallback gate (128^2 BK=32, B reg-staged from f32 Wg) — only if d_ws < 132 MiB.
__global__ __launch_bounds__(256) void gemm_gate128_f32(
    const unsigned short* __restrict__ fg, const unsigned short* __restrict__ fs,
    const float* __restrict__ Wg, const float* __restrict__ bg,
    float* __restrict__ out0, float* __restrict__ out1) {
  const int bid = xcd_swz(blockIdx.x, 2048);
  const int mt = bid >> 3, nt = bid & 7;
  const int row0 = mt * 128, col0 = nt * 128;

  __shared__ __align__(16) unsigned short As[128 * 32];
  __shared__ __align__(16) unsigned short Bss[128 * 32];

  const int tid = threadIdx.x;
  const int lane = tid & 63, wave = tid >> 6;
  const int wr = wave >> 1, wc = wave & 1;
  const int lr = lane & 15, lk = lane >> 4;
  const int sr = tid >> 2, sc = (tid & 3) * 8;

  f32x4v acc[4][4] = {};
  const int ab = (wr * 64 + lr) * 4 + lk;
  const int bb = (wc * 64 + lr) * 4 + lk;

  for (int kt = 0; kt < 64; ++kt) {
    const unsigned short* Asrc = (kt < 32) ? fg : fs;
    const int k0 = (kt & 31) * 32;
    const int kw = kt * 32;
    __syncthreads();
    gl_lds16(&Asrc[(size_t)(row0 + sr) * DDIM + k0 + sc], &As[sr * 32 + sc]);
    gl_lds16(&Asrc[(size_t)(row0 + 64 + sr) * DDIM + k0 + sc], &As[(64 + sr) * 32 + sc]);
    stage_f32(Wg, 2048, col0, kw, Bss, tid);
    __syncthreads();
    mfma_tile128(As, Bss, ab, bb, acc);
  }

#pragma unroll
  for (int n = 0; n < 4; ++n) {
    int col = col0 + wc * 64 + n * 16 + lr;
    float bgv = bg[col];
#pragma unroll
    for (int m = 0; m < 4; ++m) {
      int rbase = row0 + wr * 64 + m * 16 + lk * 4;
#pragma unroll
      for (int r = 0; r < 4; ++r) {
        size_t idx = (size_t)(rbase + r) * DDIM + col;
        float g = 1.f / (1.f + __expf(-(acc[m][n][r] + bgv)));
        float a = bf2f(fg[idx]), b = bf2f(fs[idx]);
        out0[idx] = g * a + (1.f - g) * b;
        out1[idx] = g;
      }
    }
  }
}

// In-place LayerNorm over rows of Z. 1 wave per row.
__global__ __launch_bounds__(256) void ln_kernel(
    unsigned short* __restrict__ Z,
    const float* __restrict__ gam_g, const float* __restrict__ bet_g,
    const float* __restrict__ gam_s, const float* __restrict__ bet_s) {
  int row = blockIdx.x * 4 + (threadIdx.x >> 6);
  int lane = threadIdx.x & 63;
  const float* gam = (row < BROWS) ? gam_g : gam_s;
  const float* bet = (row < BROWS) ? bet_g : bet_s;
  unsigned short* zr = Z + (size_t)row * DDIM;

  uint4 v0 = *(const uint4*)(zr + lane * 8);
  uint4 v1 = *(const uint4*)(zr + 512 + lane * 8);
  const unsigned short* u0 = (const unsigned short*)&v0;
  const unsigned short* u1 = (const unsigned short*)&v1;
  float x[16];
  float s = 0.f, sq = 0.f;
#pragma unroll
  for (int e = 0; e < 8; ++e) { x[e] = bf2f(u0[e]); x[8 + e] = bf2f(u1[e]); }
#pragma unroll
  for (int i = 0; i < 16; ++i) { s += x[i]; sq += x[i] * x[i]; }
#pragma unroll
  for (int o = 32; o; o >>= 1) { s += __shfl_xor(s, o); sq += __shfl_xor(sq, o); }
  float mu = s * (1.f / 1024.f);
  float var = sq * (1.f / 1024.f) - mu * mu;
  float rstd = rsqrtf(var + 1e-5f);

  float4 g0 = *(const float4*)(gam + lane * 8);
  float4 g1 = *(const float4*)(gam + lane * 8 + 4);
  float4 g2 = *(const float4*)(gam + 512 + lane * 8);
  float4 g3 = *(const float4*)(gam + 512 + lane * 8 + 4);
  float4 b0 = *(const float4*)(bet + lane * 8);
  float4 b1 = *(const float4*)(bet + lane * 8 + 4);
  float4 b2 = *(const float4*)(bet + 512 + lane * 8);
  float4 b3 = *(const float4*)(bet + 512 + lane * 8 + 4);
  float gg[16] = {g0.x,g0.y,g0.z,g0.w,g1.x,g1.y,g1.z,g1.w,
                  g2.x,g2.y,g2.z,g2.w,g3.x,g3.y,g3.z,g3.w};
  float bb[16] = {b0.x,b0.y,b0.z,b0.w,b1.x,b1.y,b1.z,b1.w,
                  b2.x,b2.y,b2.z,b2.w,b3.x,b3.y,b3.z,b3.w};

  union { uint4 q; unsigned short h[8]; } o0, o1;
#pragma unroll
  for (int e = 0; e < 8; ++e) {
    o0.h[e] = f2bf((x[e] - mu) * rstd * gg[e] + bb[e]);
    o1.h[e] = f2bf((x[8 + e] - mu) * rstd * gg[8 + e] + bb[8 + e]);
  }
  *(uint4*)(zr + lane * 8) = o0.q;
  *(uint4*)(zr + 512 + lane * 8) = o1.q;
}

extern "C" void kernel_launch(void* const* d_in, const int* in_sizes, int n_in,
                              void* d_out, int out_size, void* d_ws, size_t ws_size,
                              hipStream_t stream) {
  const float* graph  = (const float*)d_in[0];
  const float* smiles = (const float*)d_in[1];
  const float* Wv_gs  = (const float*)d_in[5];
  const float* bv_gs  = (const float*)d_in[8];
  const float* Wo_gs  = (const float*)d_in[9];
  const float* bo_gs  = (const float*)d_in[10];
  const float* Wv_sg  = (const float*)d_in[13];
  const float* bv_sg  = (const float*)d_in[16];
  const float* Wo_sg  = (const float*)d_in[17];
  const float* bo_sg  = (const float*)d_in[18];
  const float* ln_gg  = (const float*)d_in[19];
  const float* ln_gb  = (const float*)d_in[20];
  const float* ln_sg  = (const float*)d_in[21];
  const float* ln_sb  = (const float*)d_in[22];
  const float* Wg     = (const float*)d_in[23];
  const float* bg     = (const float*)d_in[24];

  char* ob = (char*)d_out;
  unsigned short* Xg_b  = (unsigned short*)ob;                        // 64 MiB
  unsigned short* Xs_b  = (unsigned short*)(ob + (64u << 20));        // 64 MiB
  unsigned short* Wc_gs = (unsigned short*)(ob + (128u << 20));       // 2 MiB
  unsigned short* Wc_sg = (unsigned short*)(ob + (130u << 20));       // 2 MiB
  float* bc_gs = (float*)(ob + (132u << 20));
  float* bc_sg = (float*)(ob + (132u << 20) + 4096);

  unsigned short* Zg = (unsigned short*)d_ws;
  unsigned short* Zs = Zg + (size_t)BROWS * DDIM;
  const bool fast = ws_size >= ((size_t)132 << 20);
  unsigned short* WgB = (unsigned short*)((char*)d_ws + ((size_t)128 << 20));

  float* out0 = (float*)d_out;
  float* out1 = out0 + (size_t)BROWS * DDIM;

  cvt_x<<<dim3(65536), dim3(256), 0, stream>>>(graph, smiles, Xg_b, Xs_b);
  bias_combine<<<dim3(8), dim3(256), 0, stream>>>(Wo_gs, bv_gs, bo_gs, Wo_sg, bv_sg, bo_sg,
                                                  bc_gs, bc_sg);
  combine_kernel<<<dim3(64, 2), dim3(256), 0, stream>>>(Wo_gs, Wv_gs, Wo_sg, Wv_sg,
                                                        Wc_gs, Wc_sg);
  if (fast) cvt_wg<<<dim3(2048), dim3(256), 0, stream>>>(Wg, WgB);
  gemm_branch<<<dim3(2048, 2), dim3(256), 0, stream>>>(Xs_b, Xg_b, Wc_gs, Wc_sg,
                                                       bc_gs, bc_sg, Zg, Zs);
  ln_kernel<<<dim3(16384), dim3(256), 0, stream>>>(Zg, ln_gg, ln_gb, ln_sg, ln_sb);
  if (fast)
    gemm_gate<<<dim3(2048), dim3(256), 0, stream>>>(Zg, Zs, WgB, bg, out0, out1);
  else
    gemm_gate128_f32<<<dim3(2048), dim3(256), 0, stream>>>(Zg, Zs, Wg, bg, out0, out1);
}